// Round 11
// baseline (392.811 us; speedup 1.0000x reference)
//
#include <hip/hip_runtime.h>
#include <hip/hip_bf16.h>

// FastUpConvolution on MI355X — round 11: R10 (register-resident W via
// MFMA-native global layout, barriers only around X staging) + dbuf parity
// fix. One implicit GEMM C[1024][16384] = W[1024][4608] * X[16384][4608]^T
// over NHWC-padded x (zero-padded taps), bf16 MFMA, f32 I/O.
//
// R10 post-mortem: 9 taps/chunk is ODD, so the A-frag register double
// buffer's (tap&1) parity flipped across chunks — odd chunks consumed
// stale/wrong-tap W fragments (absmax 2.60). Fix: after each chunk's tap
// loop, copy abuf[1] -> abuf[0] so every chunk starts with tap0 data in
// abuf[0]. Everything else identical to R10.
//
// ws layout:
//   x_t   : bf16 [16][34][34][512]  @ 0          (18,939,904 B)
//   W_t   : bf16 MFMA-frag layout   @ 18,939,904 ( 9,437,184 B)
//   bias  : f32  [1024]             @ 28,377,088 (     4,096 B)  row=co*4+q
//   stats : f32  [512] sum|sumsq    @ 28,381,184 (     2,048 B)

typedef unsigned short ushort_t;
typedef __attribute__((ext_vector_type(8))) short short8;
typedef __attribute__((ext_vector_type(4))) float floatx4;
typedef __attribute__((ext_vector_type(2))) float floatx2;
typedef __attribute__((ext_vector_type(4))) unsigned short u16x4;
typedef __attribute__((ext_vector_type(8))) unsigned short u16x8;
typedef __attribute__((ext_vector_type(4))) unsigned int u32x4;

#define XT_OFF    0u
#define WT_OFF    18939904u
#define BIAS_OFF  28377088u
#define STATS_OFF 28381184u

#define NSITES 204            // 6 rows x 34 cols X footprint, 128 B/site

// W_t byte strides (panel = 128 n-rows)
#define W_KS   8192           // 8 g-groups x 1024
#define W_TAP  16384          // 2 ks
#define W_CHK  147456         // 9 taps
#define W_PAN  1179648        // 8 chunks

#define ASYNC16(g, l) __builtin_amdgcn_global_load_lds( \
    (const __attribute__((address_space(1))) void*)(g), \
    (__attribute__((address_space(3))) void*)(l), 16, 0, 0)

__device__ __forceinline__ ushort_t f2bf(float f) {
  unsigned int u = __builtin_bit_cast(unsigned int, f);
  u += 0x7fffu + ((u >> 16) & 1u);   // RNE (values finite here)
  return (ushort_t)(u >> 16);
}

// -------------------------------------------------------------- prep_all ---
// blocks 0..543: prep_x (f32 NCHW -> bf16 NHWC zero-padded x_t).
// blocks 544..1567: prep_w into MFMA-frag layout + bias; block 544 zeros
// stats. For global W row r = co*4+q: panel=r>>7, g=(r&127)>>4, ri=r&15.
// ci -> chunk=ci>>6, ks=(ci>>5)&1, kg=(ci>>3)&3, e=ci&7; lane = kg*16+ri.
__global__ __launch_bounds__(256) void prep_all(
    const float* __restrict__ x, ushort_t* __restrict__ xt,
    const float* __restrict__ w1, const float* __restrict__ w2,
    const float* __restrict__ w3, const float* __restrict__ w4,
    const float* __restrict__ b1, const float* __restrict__ b2,
    const float* __restrict__ b3, const float* __restrict__ b4,
    ushort_t* __restrict__ wt, float* __restrict__ bias,
    float* __restrict__ stats) {
  __shared__ ushort_t lds[128 * 36];
  const int t = threadIdx.x;
  if (blockIdx.x >= 544) {            // ---- prep_w path ----
    const int nout = blockIdx.x - 544;
    if (nout == 0 && t < 256) { stats[t] = 0.f; stats[256 + t] = 0.f; }
    const int q = nout >> 8, co = nout & 255;
    const int row = co * 4 + q;
    const int panel = row >> 7, g = (row & 127) >> 4, riw = row & 15;
    const float* wsrc; const float* bsrc; int khl, kwl;
    if (q == 0)      { wsrc = w1; bsrc = b1; khl = 3; kwl = 3; }
    else if (q == 1) { wsrc = w2; bsrc = b2; khl = 2; kwl = 3; }
    else if (q == 2) { wsrc = w3; bsrc = b3; khl = 3; kwl = 2; }
    else             { wsrc = w4; bsrc = b4; khl = 2; kwl = 2; }
    if (t == 0) bias[row] = bsrc[co];
    // base (in ushorts) for this row's (g, ri) within each [..][ks] slab
    ushort_t* dstp = wt + (size_t)panel * (W_PAN / 2) + g * 512 + riw * 8;
    for (int tap = 0; tap < 9; ++tap) {
      const int dh = tap / 3, dw = tap % 3;
      const bool valid = (dh < khl) && (dw < kwl);
#pragma unroll
      for (int cc = 0; cc < 2; ++cc) {
        const int ci = cc * 256 + t;
        ushort_t v = 0;
        if (valid)
          v = f2bf(wsrc[(((size_t)co * 512 + ci) * khl + dh) * kwl + dw]);
        const int chunk = ci >> 6, ks = (ci >> 5) & 1;
        const int kg = (ci >> 3) & 3, e = ci & 7;
        dstp[(size_t)chunk * (W_CHK / 2) + tap * (W_TAP / 2) +
             ks * (W_KS / 2) + kg * 128 + e] = v;
      }
    }
    return;
  }
  // ---- prep_x path ----
  const int b = blockIdx.x;
  const int n = b / 34, hp = b % 34;
  ushort_t* dst = xt + (size_t)(n * 34 + hp) * (34 * 512);
  if (hp == 0 || hp == 33) {
    u32x4 z = {0u, 0u, 0u, 0u};
    for (int i = t; i < 2176; i += 256) ((u32x4*)dst)[i] = z;
    return;
  }
  const int h = hp - 1;
  {
    u32x4 z = {0u, 0u, 0u, 0u};
    if (t < 64) ((u32x4*)dst)[t] = z;
    else if (t < 128) ((u32x4*)(dst + 33 * 512))[t - 64] = z;
  }
  const size_t base = (size_t)n * 524288 + (size_t)h * 32;
  for (int ci0 = 0; ci0 < 512; ci0 += 128) {
    __syncthreads();
    {
      const int cil = t >> 3;
      const int w4 = (t & 7) << 2;
#pragma unroll
      for (int cc = 0; cc < 4; ++cc) {
        const int ci = cil + cc * 32;
        floatx4 v = *(const floatx4*)(x + base + (size_t)(ci0 + ci) * 1024 + w4);
        u16x4 hv;
#pragma unroll
        for (int j = 0; j < 4; ++j) hv[j] = f2bf(v[j]);
        *(u16x4*)&lds[ci * 36 + w4] = hv;
      }
    }
    __syncthreads();
    {
      const int w = t & 31;
      const int j8 = t >> 5;
#pragma unroll
      for (int cc2 = 0; cc2 < 2; ++cc2) {
        const int cil = cc2 * 64 + j8 * 8;
        u16x8 v;
#pragma unroll
        for (int j = 0; j < 8; ++j) v[j] = lds[(cil + j) * 36 + w];
        *(u16x8*)(dst + (w + 1) * 512 + ci0 + cil) = v;
      }
    }
  }
}

// ------------------------------------------------------------------ gemm ---
// Block 128 m (4h x 32w) x 128 n; 4 waves 2x2, 4x4 frags of 16x16x32 bf16.
// X: ASYNC16-staged footprint per 64-ci chunk (XOR swizzle), one barrier
// pair per chunk. W: register pipeline, one coalesced 1KB load per frag
// (lane*16 contiguous), prefetched one tap ahead, NO barriers. After each
// chunk (9 taps, odd), abuf[1] is copied to abuf[0] to restore dbuf parity.
__global__ __launch_bounds__(256) void gemm_kernel(
    const ushort_t* __restrict__ xt, const ushort_t* __restrict__ wt,
    const float* __restrict__ bias, float* __restrict__ out,
    float* __restrict__ stats) {
  __shared__ char ldsX[NSITES * 128];    // 26,112 B
  const int tid = threadIdx.x;
  const int bx = blockIdx.x;
  const int bn = bx & 7, bm = bx >> 3;
  const int n0 = bn << 7;
  const int n_img = bm >> 3;
  const int h0p = (bm & 7) << 2;        // first padded x_t row of footprint
  const int wv = tid >> 6, lane = tid & 63;
  const int ri = lane & 15, kg = lane >> 4;
  const int wm = (wv & 1) << 6, wn = (wv >> 1) << 6;

  // ---- X staging pointers (XOR swizzle at issue), as verified in R7 ----
  const char* xgp[7];
  char* xlp[7];
  {
    const char* xg = (const char*)(xt + (size_t)(n_img * 34 + h0p) * (34 * 512));
#pragma unroll
    for (int p = 0; p < 7; ++p) {
      const int idx = p * 256 + tid;
      const int site = idx >> 3, slot = idx & 7;
      const int c = slot ^ (site & 7);
      xgp[p] = xg + site * 1024 + (c << 4);
      xlp[p] = ldsX + idx * 16;
    }
  }

  // ---- W register-pipeline base: this wave's g-group + lane offset ----
  const char* wpan = (const char*)wt + (size_t)bn * W_PAN + (wn >> 4) * 1024 +
                     lane * 16;

  floatx4 acc[4][4] = {};
  int bsite[4];
#pragma unroll
  for (int fj = 0; fj < 4; ++fj)
    bsite[fj] = ((wm >> 5) + (fj >> 1)) * 34 + ((fj & 1) << 4) + ri;

  u32x4 abuf[2][8];
#pragma unroll
  for (int k = 0; k < 2; ++k)
#pragma unroll
    for (int f = 0; f < 4; ++f)
      abuf[0][k * 4 + f] = *(const u32x4*)(wpan + k * W_KS + f * 1024);

  for (int chunk = 0; chunk < 8; ++chunk) {
    const int cb = chunk << 7;
#pragma unroll
    for (int p = 0; p < 6; ++p) ASYNC16(xgp[p] + cb, xlp[p]);
    if (tid < 96) ASYNC16(xgp[6] + cb, xlp[6]);   // tail: 1632 = 6*256+96
    __syncthreads();                     // drain -> X chunk visible
#pragma unroll
    for (int tap = 0; tap < 9; ++tap) {
      // prefetch next tap's A-frags into the other register buffer
      if (tap < 8 || chunk < 7) {
        const char* np = wpan +
            ((tap < 8) ? ((size_t)chunk * W_CHK + (tap + 1) * W_TAP)
                       : ((size_t)(chunk + 1) * W_CHK));
#pragma unroll
        for (int k = 0; k < 2; ++k)
#pragma unroll
          for (int f = 0; f < 4; ++f)
            abuf[(tap + 1) & 1][k * 4 + f] =
                *(const u32x4*)(np + k * W_KS + f * 1024);
      }
      const u32x4* ab = abuf[tap & 1];
      const int tapsite = (tap / 3) * 34 + (tap % 3);
      const int tapo = tapsite * 128;
#pragma unroll
      for (int ks = 0; ks < 2; ++ks) {
        const int c = (ks << 2) + kg;    // 16B chunk index within X row
        short8 a4[4], b4[4];
#pragma unroll
        for (int f = 0; f < 4; ++f)
          a4[f] = __builtin_bit_cast(short8, ab[ks * 4 + f]);
#pragma unroll
        for (int fj = 0; fj < 4; ++fj) {
          const int srow = bsite[fj] + tapsite;
          b4[fj] = *(const short8*)(ldsX + bsite[fj] * 128 + tapo +
                                    ((c ^ (srow & 7)) << 4));
        }
#pragma unroll
        for (int fi = 0; fi < 4; ++fi)
#pragma unroll
          for (int fj = 0; fj < 4; ++fj)
            acc[fi][fj] = __builtin_amdgcn_mfma_f32_16x16x32_bf16(
                a4[fi], b4[fj], acc[fi][fj], 0, 0, 0);
      }
    }
    // 9 taps flipped parity: tap8's prefetch (next chunk's tap0) landed in
    // abuf[1], but the next chunk reads tap0 from abuf[0]. Restore parity.
    if (chunk < 7) {
#pragma unroll
      for (int i = 0; i < 8; ++i) abuf[0][i] = abuf[1][i];
    }
    __syncthreads();   // X readers done before next chunk's ASYNC16 overwrite
  }

  // ---- epilogue: +bias, dense 2x2 pixel-shuffle writes, fused BN stats ----
  // D layout: col=lane&15 (m), row=quad*4+reg (n); interleaved rows => reg=q.
  const int quad = kg, colL = ri;
#pragma unroll
  for (int fi = 0; fi < 4; ++fi) {
    const int co = ((n0 + wn + (fi << 4)) >> 2) + quad;
    const floatx4 bv = *(const floatx4*)(bias + n0 + wn + (fi << 4) + (quad << 2));
    float s = 0.f, s2 = 0.f;
    float* obase = out + ((size_t)(n_img * 256 + co) << 12);
#pragma unroll
    for (int fj = 0; fj < 4; ++fj) {
      const int mb = wm + (fj << 4) + colL;       // m within block
      const int hl = mb >> 5, w = mb & 31;
      const int h = h0p + hl;                     // global h (0..31)
      float v0 = acc[fi][fj][0] + bv[0];
      float v1 = acc[fi][fj][1] + bv[1];
      float v2 = acc[fi][fj][2] + bv[2];
      float v3 = acc[fi][fj][3] + bv[3];
      s += (v0 + v1) + (v2 + v3);
      s2 += v0 * v0 + v1 * v1 + v2 * v2 + v3 * v3;
      float* p = obase + (h << 7) + (w << 1);     // row 2h, col 2w
      floatx2 e = {v0, v2};
      floatx2 o = {v1, v3};
      *(floatx2*)p = e;
      *(floatx2*)(p + 64) = o;
    }
#pragma unroll
    for (int off = 1; off < 16; off <<= 1) {
      s += __shfl_xor(s, off);
      s2 += __shfl_xor(s2, off);
    }
    if (colL == 0) {
      atomicAdd(&stats[co], s);
      atomicAdd(&stats[256 + co], s2);
    }
  }
}

// -------------------------------------------------------------- bn_apply ---
__global__ __launch_bounds__(256) void bn_apply(
    float* __restrict__ y, const float* __restrict__ stats,
    const float* __restrict__ gamma, const float* __restrict__ beta) {
  const int b = blockIdx.x;
  const int co = b & 255;
  const int t = threadIdx.x;
  const float mean = stats[co] * (1.f / 65536.f);
  const float var = stats[256 + co] * (1.f / 65536.f) - mean * mean;
  const float rstd = rsqrtf(var + 1e-5f);
  const float scale = rstd * gamma[co];
  const float shift = beta[co] - mean * scale;
  float* p = y + (size_t)b * 4096;
#pragma unroll
  for (int it = 0; it < 4; ++it) {
    floatx4* q = (floatx4*)(p + (it * 256 + t) * 4);
    floatx4 v = *q;
#pragma unroll
    for (int e = 0; e < 4; ++e) v[e] = fmaxf(v[e] * scale + shift, 0.f);
    *q = v;
  }
}

// ---------------------------------------------------------------- launch ---
extern "C" void kernel_launch(void* const* d_in, const int* in_sizes, int n_in,
                              void* d_out, int out_size, void* d_ws,
                              size_t ws_size, hipStream_t stream) {
  const float* x  = (const float*)d_in[0];
  const float* w1 = (const float*)d_in[1];
  const float* b1 = (const float*)d_in[2];
  const float* w2 = (const float*)d_in[3];
  const float* b2 = (const float*)d_in[4];
  const float* w3 = (const float*)d_in[5];
  const float* b3 = (const float*)d_in[6];
  const float* w4 = (const float*)d_in[7];
  const float* b4 = (const float*)d_in[8];
  const float* gamma = (const float*)d_in[9];
  const float* beta  = (const float*)d_in[10];
  float* out = (float*)d_out;

  char* ws = (char*)d_ws;
  ushort_t* xt   = (ushort_t*)(ws + XT_OFF);
  ushort_t* wt   = (ushort_t*)(ws + WT_OFF);
  float*    bias = (float*)(ws + BIAS_OFF);
  float*    st   = (float*)(ws + STATS_OFF);

  prep_all<<<544 + 1024, 256, 0, stream>>>(x, xt, w1, w2, w3, w4,
                                           b1, b2, b3, b4, wt, bias, st);
  gemm_kernel<<<1024, 256, 0, stream>>>(xt, wt, bias, out, st);
  bn_apply<<<4096, 256, 0, stream>>>(out, st, gamma, beta);
}

// Round 12
// 336.723 us; speedup vs baseline: 1.1666x; 1.1666x over previous
//
#include <hip/hip_runtime.h>
#include <hip/hip_bf16.h>

// FastUpConvolution on MI355X — round 12: per-quadrant tap lists (25/36 of
// the unified-GEMM work) on the verified R7 structure.
// C quadrant q (n-rows q*256..q*256+255) needs only its conv's taps:
// q0=3x3: 9, q1=2x3: {0,1,2,3,4,5}, q2=3x2: {0,1,3,4,6,7}, q3=2x2:
// {0,1,3,4}. Blocks are quadrant-pure (q = bn>>1) and run only active taps.
// Staging/MFMA identical to R7 (ASYNC16 + XOR swizzle + per-tap W dbuf in
// LDS). Epilogue: per-quadrant stride-2 scatter + fused BN-stat atomics.
//
// R11 post-mortem: register-resident W gave 2 waves/SIMD (VGPR+AGPR=188)
// and per-wave VMEM waits -> MfmaUtil 24%. R7 remains the best structure
// (165 us, MFMA busy 68 us = bf16 floor for K=4*4608). This round cuts the
// WORK: MFMA floor 68->47 us, LDS-pipe 92->64 us, barriers x0.69.
//
// ws layout:
//   x_t   : bf16 [16][34][34][512]  @ 0          (18,939,904 B)
//   W_t   : bf16 [1024 rows][9*512] @ 18,939,904 ( 9,437,184 B)  row=q*256+co
//   bias  : f32  [1024]             @ 28,377,088 (     4,096 B)  row=q*256+co
//   stats : f32  [512] sum|sumsq    @ 28,381,184 (     2,048 B)

typedef unsigned short ushort_t;
typedef __attribute__((ext_vector_type(8))) short short8;
typedef __attribute__((ext_vector_type(4))) float floatx4;
typedef __attribute__((ext_vector_type(4))) unsigned short u16x4;
typedef __attribute__((ext_vector_type(8))) unsigned short u16x8;
typedef __attribute__((ext_vector_type(4))) unsigned int u32x4;

#define XT_OFF    0u
#define WT_OFF    18939904u
#define BIAS_OFF  28377088u
#define STATS_OFF 28381184u

#define NSITES 204            // 6 rows x 34 cols X footprint, 128 B/site

#define ASYNC16(g, l) __builtin_amdgcn_global_load_lds( \
    (const __attribute__((address_space(1))) void*)(g), \
    (__attribute__((address_space(3))) void*)(l), 16, 0, 0)

__device__ __forceinline__ ushort_t f2bf(float f) {
  unsigned int u = __builtin_bit_cast(unsigned int, f);
  u += 0x7fffu + ((u >> 16) & 1u);   // RNE (values finite here)
  return (ushort_t)(u >> 16);
}

// -------------------------------------------------------------- prep_all ---
// blocks 0..543: prep_x (f32 NCHW -> bf16 NHWC zero-padded x_t).
// blocks 544..1567: prep_w (row = q*256+co = nout, zero-padded taps) + bias;
// block 544 zeros stats.
__global__ __launch_bounds__(256) void prep_all(
    const float* __restrict__ x, ushort_t* __restrict__ xt,
    const float* __restrict__ w1, const float* __restrict__ w2,
    const float* __restrict__ w3, const float* __restrict__ w4,
    const float* __restrict__ b1, const float* __restrict__ b2,
    const float* __restrict__ b3, const float* __restrict__ b4,
    ushort_t* __restrict__ wt, float* __restrict__ bias,
    float* __restrict__ stats) {
  __shared__ ushort_t lds[128 * 36];
  const int t = threadIdx.x;
  if (blockIdx.x >= 544) {            // ---- prep_w path ----
    const int nout = blockIdx.x - 544;
    if (nout == 0 && t < 256) { stats[t] = 0.f; stats[256 + t] = 0.f; }
    const int q = nout >> 8, co = nout & 255;
    const float* wsrc; const float* bsrc; int khl, kwl;
    if (q == 0)      { wsrc = w1; bsrc = b1; khl = 3; kwl = 3; }
    else if (q == 1) { wsrc = w2; bsrc = b2; khl = 2; kwl = 3; }
    else if (q == 2) { wsrc = w3; bsrc = b3; khl = 3; kwl = 2; }
    else             { wsrc = w4; bsrc = b4; khl = 2; kwl = 2; }
    if (t == 0) bias[nout] = bsrc[co];
    ushort_t* dst = wt + (size_t)nout * 4608;
    for (int tap = 0; tap < 9; ++tap) {
      const int dh = tap / 3, dw = tap % 3;
      const bool valid = (dh < khl) && (dw < kwl);
#pragma unroll
      for (int cc = 0; cc < 2; ++cc) {
        const int ci = cc * 256 + t;
        ushort_t v = 0;
        if (valid)
          v = f2bf(wsrc[(((size_t)co * 512 + ci) * khl + dh) * kwl + dw]);
        dst[tap * 512 + ci] = v;
      }
    }
    return;
  }
  // ---- prep_x path ----
  const int b = blockIdx.x;
  const int n = b / 34, hp = b % 34;
  ushort_t* dst = xt + (size_t)(n * 34 + hp) * (34 * 512);
  if (hp == 0 || hp == 33) {
    u32x4 z = {0u, 0u, 0u, 0u};
    for (int i = t; i < 2176; i += 256) ((u32x4*)dst)[i] = z;
    return;
  }
  const int h = hp - 1;
  {
    u32x4 z = {0u, 0u, 0u, 0u};
    if (t < 64) ((u32x4*)dst)[t] = z;
    else if (t < 128) ((u32x4*)(dst + 33 * 512))[t - 64] = z;
  }
  const size_t base = (size_t)n * 524288 + (size_t)h * 32;
  for (int ci0 = 0; ci0 < 512; ci0 += 128) {
    __syncthreads();
    {
      const int cil = t >> 3;
      const int w4 = (t & 7) << 2;
#pragma unroll
      for (int cc = 0; cc < 4; ++cc) {
        const int ci = cil + cc * 32;
        floatx4 v = *(const floatx4*)(x + base + (size_t)(ci0 + ci) * 1024 + w4);
        u16x4 hv;
#pragma unroll
        for (int j = 0; j < 4; ++j) hv[j] = f2bf(v[j]);
        *(u16x4*)&lds[ci * 36 + w4] = hv;
      }
    }
    __syncthreads();
    {
      const int w = t & 31;
      const int j8 = t >> 5;
#pragma unroll
      for (int cc2 = 0; cc2 < 2; ++cc2) {
        const int cil = cc2 * 64 + j8 * 8;
        u16x8 v;
#pragma unroll
        for (int j = 0; j < 8; ++j) v[j] = lds[(cil + j) * 36 + w];
        *(u16x8*)(dst + (w + 1) * 512 + ci0 + cil) = v;
      }
    }
  }
}

// ------------------------------------------------------------------ gemm ---
// Block 128 m (4h x 32w) x 128 n (one quadrant); 4 waves 2x2, 4x4 frags of
// 16x16x32 bf16. K = 8 chunks x 64 ci; per chunk ASYNC16-stage X footprint
// once (XOR swizzle) + iterate the quadrant's ACTIVE taps only (9/6/6/4)
// with per-tap W dbuf in LDS, one barrier per tap.
__global__ __launch_bounds__(256) void gemm_kernel(
    const ushort_t* __restrict__ xt, const ushort_t* __restrict__ wt,
    const float* __restrict__ bias, float* __restrict__ out,
    float* __restrict__ stats) {
  __shared__ char ldsX[NSITES * 128];    // 26,112 B
  __shared__ char ldsW[2][128 * 128];    // 2 x 16,384 B
  const int tid = threadIdx.x;
  const int bx = blockIdx.x;
  const int bn = bx & 7, bm = bx >> 3;
  const int n0 = bn << 7;
  const int q = bn >> 1;                // quadrant of this n-panel
  const int n_img = bm >> 3;
  const int h0p = (bm & 7) << 2;        // first padded x_t row of footprint
  const int wv = tid >> 6, lane = tid & 63;
  const int ri = lane & 15, kg = lane >> 4;
  const int wm = (wv & 1) << 6, wn = (wv >> 1) << 6;

  // active tap list (packed nibbles, LSB first) + count, per quadrant
  const unsigned long long pack =
      (q == 0) ? 0x876543210ull : (q == 1) ? 0x543210ull
                                : (q == 2) ? 0x764310ull : 0x4310ull;
  const int T = (q == 0) ? 9 : (q == 3) ? 4 : 6;

  // ---- X staging pointers (XOR swizzle at issue), verified R7 ----
  const char* xgp[7];
  char* xlp[7];
  {
    const char* xg = (const char*)(xt + (size_t)(n_img * 34 + h0p) * (34 * 512));
#pragma unroll
    for (int p = 0; p < 7; ++p) {
      const int idx = p * 256 + tid;
      const int site = idx >> 3, slot = idx & 7;
      const int c = slot ^ (site & 7);
      xgp[p] = xg + site * 1024 + (c << 4);
      xlp[p] = ldsX + idx * 16;
    }
  }
  // W staging: idx over 1024 = 128 rows x 8 slots.
  const char* wgp[4];
  char* wlp0[4];
  char* wlp1[4];
#pragma unroll
  for (int p = 0; p < 4; ++p) {
    const int idx = p * 256 + tid;
    const int row = idx >> 3, slot = idx & 7;
    const int c = slot ^ (row & 7);
    wgp[p] = (const char*)wt + (size_t)(n0 + row) * 9216 + (c << 4);
    wlp0[p] = ldsW[0] + idx * 16;
    wlp1[p] = ldsW[1] + idx * 16;
  }

  floatx4 acc[4][4] = {};
  int arow[4], bsite[4];
#pragma unroll
  for (int f = 0; f < 4; ++f) arow[f] = wn + (f << 4) + ri;
#pragma unroll
  for (int fj = 0; fj < 4; ++fj)
    bsite[fj] = ((wm >> 5) + (fj >> 1)) * 34 + ((fj & 1) << 4) + ri;

  const int tap0off = ((int)(pack & 15)) << 10;
  for (int chunk = 0; chunk < 8; ++chunk) {
    const int cb = chunk << 7;
#pragma unroll
    for (int p = 0; p < 6; ++p) ASYNC16(xgp[p] + cb, xlp[p]);
    if (tid < 96) ASYNC16(xgp[6] + cb, xlp[6]);   // tail: 1632 = 6*256+96
#pragma unroll
    for (int p = 0; p < 4; ++p) ASYNC16(wgp[p] + tap0off + cb, wlp0[p]);
    __syncthreads();                     // drain -> X + W(first tap) visible
    for (int i = 0; i < T; ++i) {
      const int tap = (int)((pack >> (4 * i)) & 15);
      if (i < T - 1) {                   // prefetch next active tap
        const int ntap = (int)((pack >> (4 * i + 4)) & 15);
        const int noff = (ntap << 10) + cb;
        if (i & 1) {
#pragma unroll
          for (int p = 0; p < 4; ++p) ASYNC16(wgp[p] + noff, wlp0[p]);
        } else {
#pragma unroll
          for (int p = 0; p < 4; ++p) ASYNC16(wgp[p] + noff, wlp1[p]);
        }
      }
      const char* wb = ldsW[i & 1];
      const int tapsite = tap + 31 * ((tap * 11) >> 5);  // dh*34+dw
      const int tapo = tapsite * 128;
#pragma unroll
      for (int ks = 0; ks < 2; ++ks) {
        const int c = (ks << 2) + kg;    // 16B chunk index within row
        short8 a4[4], b4[4];
#pragma unroll
        for (int f = 0; f < 4; ++f)
          a4[f] = *(const short8*)(wb + arow[f] * 128 +
                                   ((c ^ (arow[f] & 7)) << 4));
#pragma unroll
        for (int fj = 0; fj < 4; ++fj) {
          const int srow = bsite[fj] + tapsite;
          b4[fj] = *(const short8*)(ldsX + bsite[fj] * 128 + tapo +
                                    ((c ^ (srow & 7)) << 4));
        }
#pragma unroll
        for (int fi = 0; fi < 4; ++fi)
#pragma unroll
          for (int fj = 0; fj < 4; ++fj)
            acc[fi][fj] = __builtin_amdgcn_mfma_f32_16x16x32_bf16(
                a4[fi], b4[fj], acc[fi][fj], 0, 0, 0);
      }
      __syncthreads();   // readers of wb & X done; W(next) drained
    }
  }

  // ---- epilogue: +bias, per-quadrant stride-2 scatter, fused BN stats ----
  // D layout: col=lane&15 (m), row=quad*4+reg (n). Quadrant-pure panel:
  // co = (bn&1)*128 + wn + fi*16 + quad*4 + reg; (ph,pw) from q.
  const int quad = kg, colL = ri;
  const int ph = q & 1, pw = q >> 1;
#pragma unroll
  for (int fi = 0; fi < 4; ++fi) {
#pragma unroll
    for (int reg = 0; reg < 4; ++reg) {
      const int co = ((bn & 1) << 7) + wn + (fi << 4) + (quad << 2) + reg;
      const float bv = bias[(q << 8) + co];
      float s = 0.f, s2 = 0.f;
      float* obase = out + ((size_t)(n_img * 256 + co) << 12) + (ph << 6) + pw;
#pragma unroll
      for (int fj = 0; fj < 4; ++fj) {
        const int mb = wm + (fj << 4) + colL;     // m within block
        const int h = h0p + (mb >> 5), w = mb & 31;
        const float v = acc[fi][fj][reg] + bv;
        s += v;
        s2 += v * v;
        obase[(h << 7) + (w << 1)] = v;           // (2h+ph)*64 + 2w+pw
      }
#pragma unroll
      for (int off = 1; off < 16; off <<= 1) {
        s += __shfl_xor(s, off);
        s2 += __shfl_xor(s2, off);
      }
      if (colL == 0) {
        atomicAdd(&stats[co], s);
        atomicAdd(&stats[256 + co], s2);
      }
    }
  }
}

// -------------------------------------------------------------- bn_apply ---
__global__ __launch_bounds__(256) void bn_apply(
    float* __restrict__ y, const float* __restrict__ stats,
    const float* __restrict__ gamma, const float* __restrict__ beta) {
  const int b = blockIdx.x;
  const int co = b & 255;
  const int t = threadIdx.x;
  const float mean = stats[co] * (1.f / 65536.f);
  const float var = stats[256 + co] * (1.f / 65536.f) - mean * mean;
  const float rstd = rsqrtf(var + 1e-5f);
  const float scale = rstd * gamma[co];
  const float shift = beta[co] - mean * scale;
  float* p = y + (size_t)b * 4096;
#pragma unroll
  for (int it = 0; it < 4; ++it) {
    floatx4* qp = (floatx4*)(p + (it * 256 + t) * 4);
    floatx4 v = *qp;
#pragma unroll
    for (int e = 0; e < 4; ++e) v[e] = fmaxf(v[e] * scale + shift, 0.f);
    *qp = v;
  }
}

// ---------------------------------------------------------------- launch ---
extern "C" void kernel_launch(void* const* d_in, const int* in_sizes, int n_in,
                              void* d_out, int out_size, void* d_ws,
                              size_t ws_size, hipStream_t stream) {
  const float* x  = (const float*)d_in[0];
  const float* w1 = (const float*)d_in[1];
  const float* b1 = (const float*)d_in[2];
  const float* w2 = (const float*)d_in[3];
  const float* b2 = (const float*)d_in[4];
  const float* w3 = (const float*)d_in[5];
  const float* b3 = (const float*)d_in[6];
  const float* w4 = (const float*)d_in[7];
  const float* b4 = (const float*)d_in[8];
  const float* gamma = (const float*)d_in[9];
  const float* beta  = (const float*)d_in[10];
  float* out = (float*)d_out;

  char* ws = (char*)d_ws;
  ushort_t* xt   = (ushort_t*)(ws + XT_OFF);
  ushort_t* wt   = (ushort_t*)(ws + WT_OFF);
  float*    bias = (float*)(ws + BIAS_OFF);
  float*    st   = (float*)(ws + STATS_OFF);

  prep_all<<<544 + 1024, 256, 0, stream>>>(x, xt, w1, w2, w3, w4,
                                           b1, b2, b3, b4, wt, bias, st);
  gemm_kernel<<<1024, 256, 0, stream>>>(xt, wt, bias, out, st);
  bn_apply<<<4096, 256, 0, stream>>>(out, st, gamma, beta);
}